// Round 1
// baseline (17047.150 us; speedup 1.0000x reference)
//
#include <hip/hip_runtime.h>
#include <cstddef>

#define B_ 512
#define T_ 256
#define L_ 256
#define HE_ 256
#define HT_ 512
#define OUT_ 88

__device__ __forceinline__ float sigmoidf_(float x) { return 1.f / (1.f + expf(-x)); }
// jax.nn.softplus = max(x,0) + log1p(exp(-|x|))
__device__ __forceinline__ float softplusf_(float x) { return fmaxf(x, 0.f) + log1pf(expf(-fabsf(x))); }

// ---------------------------------------------------------------------------
// Emission: 3-layer MLP over 131072 independent rows.
// Block = 256 threads, 32 rows/block. LDS ping-pong buffers (2 x 32KB).
// Thread layout for 256-col layers: cx = tid&63 owns cols [cx*4, cx*4+3],
// ry = tid>>6 owns rows [ry*8, ry*8+7]  -> 32 accumulators / thread.
// Wave = 64 consecutive tids -> same ry -> LDS reads are broadcasts (free).
// Weight reads: lane cx reads W[k][cx*4..+3] -> fully coalesced float4.
// ---------------------------------------------------------------------------
#define EROWS 32

__device__ __forceinline__ void mlp_layer256(
    const float (*__restrict__ src)[256], float (*__restrict__ dst)[256],
    const float* __restrict__ W, const float* __restrict__ bias,
    int cx, int ry, bool do_relu)
{
  float acc[8][4] = {};
  for (int k = 0; k < 256; k += 4) {
    float sv[8][4];
    #pragma unroll
    for (int r = 0; r < 8; ++r) {
      float4 tv = *(const float4*)&src[ry * 8 + r][k];
      sv[r][0] = tv.x; sv[r][1] = tv.y; sv[r][2] = tv.z; sv[r][3] = tv.w;
    }
    #pragma unroll
    for (int kk = 0; kk < 4; ++kk) {
      float4 w = *(const float4*)&W[(size_t)(k + kk) * 256 + cx * 4];
      float wa[4] = {w.x, w.y, w.z, w.w};
      #pragma unroll
      for (int r = 0; r < 8; ++r) {
        #pragma unroll
        for (int j = 0; j < 4; ++j) acc[r][j] += sv[r][kk] * wa[j];
      }
    }
  }
  float4 bv = *(const float4*)&bias[cx * 4];
  float ba[4] = {bv.x, bv.y, bv.z, bv.w};
  #pragma unroll
  for (int r = 0; r < 8; ++r) {
    float v[4];
    #pragma unroll
    for (int j = 0; j < 4; ++j) {
      v[j] = acc[r][j] + ba[j];
      if (do_relu) v[j] = fmaxf(v[j], 0.f);
    }
    *(float4*)&dst[ry * 8 + r][cx * 4] = make_float4(v[0], v[1], v[2], v[3]);
  }
}

__global__ __launch_bounds__(256) void emission_kernel(
    const float* __restrict__ zhat,
    const float* __restrict__ We1, const float* __restrict__ be1,
    const float* __restrict__ We2, const float* __restrict__ be2,
    const float* __restrict__ We3, const float* __restrict__ be3,
    float* __restrict__ xhat)
{
  __shared__ __align__(16) float buf0[EROWS][256];
  __shared__ __align__(16) float buf1[EROWS][256];
  const int tid = threadIdx.x;
  const size_t row0 = (size_t)blockIdx.x * EROWS;

  { // load 32x256 input tile, coalesced float4
    const float* src = zhat + row0 * 256;
    float* flat = &buf0[0][0];
    #pragma unroll
    for (int it = 0; it < 8; ++it) {
      int i = tid * 4 + it * 1024;
      *(float4*)&flat[i] = *(const float4*)&src[i];
    }
  }
  __syncthreads();

  const int cx = tid & 63;
  const int ry = tid >> 6;

  mlp_layer256(buf0, buf1, We1, be1, cx, ry, true);   // layer 1 -> buf1
  __syncthreads();
  mlp_layer256(buf1, buf0, We2, be2, cx, ry, true);   // layer 2 -> buf0
  __syncthreads();

  // layer 3: 256 -> 88, sigmoid. lane owns cols {lane, lane+64(<88)}
  {
    const int lane = tid & 63;
    const bool has2 = (lane + 64) < OUT_;
    float acc1[8] = {}, acc2[8] = {};
    for (int k = 0; k < 256; k += 4) {
      float sv[8][4];
      #pragma unroll
      for (int r = 0; r < 8; ++r) {
        float4 tv = *(const float4*)&buf0[ry * 8 + r][k];
        sv[r][0] = tv.x; sv[r][1] = tv.y; sv[r][2] = tv.z; sv[r][3] = tv.w;
      }
      #pragma unroll
      for (int kk = 0; kk < 4; ++kk) {
        const size_t kw = (size_t)(k + kk) * OUT_;
        const float w1 = We3[kw + lane];
        const float w2 = has2 ? We3[kw + lane + 64] : 0.f;
        #pragma unroll
        for (int r = 0; r < 8; ++r) {
          acc1[r] += sv[r][kk] * w1;
          acc2[r] += sv[r][kk] * w2;
        }
      }
    }
    const float b1 = be3[lane];
    const float b2 = has2 ? be3[lane + 64] : 0.f;
    #pragma unroll
    for (int r = 0; r < 8; ++r) {
      const size_t orow = (row0 + ry * 8 + r) * OUT_;
      xhat[orow + lane] = sigmoidf_(acc1[r] + b1);
      if (has2) xhat[orow + lane + 64] = sigmoidf_(acc2[r] + b2);
    }
  }
}

// ---------------------------------------------------------------------------
// Transition scan: carry z[b] is independent per batch row -> each block owns
// MROWS=4 rows and iterates all T=256 steps locally (no grid sync).
// 128 blocks x 256 threads. Weights streamed from L2 each step (~2.5MB/step).
// Activations staged in LDS; reads are wave-broadcasts (same address).
// ---------------------------------------------------------------------------
#define MROWS 4

__global__ __launch_bounds__(256) void transition_kernel(
    const float* __restrict__ noise, const float* __restrict__ z_init,
    const float* __restrict__ Wg1, const float* __restrict__ bg1,
    const float* __restrict__ Wg2, const float* __restrict__ bg2,
    const float* __restrict__ Wh1, const float* __restrict__ bh1,
    const float* __restrict__ Wh2, const float* __restrict__ bh2,
    const float* __restrict__ Wmu, const float* __restrict__ bmu,
    const float* __restrict__ Ws, const float* __restrict__ bs,
    float* __restrict__ mus, float* __restrict__ sigmas)
{
  __shared__ __align__(16) float zb[MROWS][L_];    // 4KB  carry
  __shared__ __align__(16) float a1g[MROWS][HT_];  // 8KB  relu(z@Wg1+bg1)
  __shared__ __align__(16) float a1h[MROWS][HT_];  // 8KB  relu(z@Wh1+bh1)
  __shared__ __align__(16) float hhb[MROWS][L_];   // 4KB  hh

  const int tid = threadIdx.x;
  const int b0 = blockIdx.x * MROWS;

  // hoist per-thread biases
  const float bg1a = bg1[tid], bg1b = bg1[tid + 256];
  const float bh1a = bh1[tid], bh1b = bh1[tid + 256];
  const float bg2r = bg2[tid], bh2r = bh2[tid];
  const float bsr = bs[tid],  bmur = bmu[tid];

  #pragma unroll
  for (int r = 0; r < MROWS; ++r)
    zb[r][tid] = z_init[(size_t)(b0 + r) * L_ + tid];
  __syncthreads();

  for (int t = 0; t < T_; ++t) {
    // ---- Phase A: a1g/a1h [4][512]; thread owns cols {tid, tid+256} ----
    float ag0[MROWS] = {}, ag1[MROWS] = {}, ah0[MROWS] = {}, ah1[MROWS] = {};
    for (int k = 0; k < L_; k += 4) {
      float zv[MROWS][4];
      #pragma unroll
      for (int r = 0; r < MROWS; ++r) {
        float4 tv = *(const float4*)&zb[r][k];
        zv[r][0] = tv.x; zv[r][1] = tv.y; zv[r][2] = tv.z; zv[r][3] = tv.w;
      }
      #pragma unroll
      for (int kk = 0; kk < 4; ++kk) {
        const size_t kw = (size_t)(k + kk) * HT_;
        const float wg0 = Wg1[kw + tid], wg1 = Wg1[kw + tid + 256];
        const float wh0 = Wh1[kw + tid], wh1 = Wh1[kw + tid + 256];
        #pragma unroll
        for (int r = 0; r < MROWS; ++r) {
          ag0[r] += zv[r][kk] * wg0; ag1[r] += zv[r][kk] * wg1;
          ah0[r] += zv[r][kk] * wh0; ah1[r] += zv[r][kk] * wh1;
        }
      }
    }
    #pragma unroll
    for (int r = 0; r < MROWS; ++r) {
      a1g[r][tid]       = fmaxf(ag0[r] + bg1a, 0.f);
      a1g[r][tid + 256] = fmaxf(ag1[r] + bg1b, 0.f);
      a1h[r][tid]       = fmaxf(ah0[r] + bh1a, 0.f);
      a1h[r][tid + 256] = fmaxf(ah1[r] + bh1b, 0.f);
    }
    __syncthreads();

    // ---- Phase B: g = sigmoid(a1g@Wg2+bg2), hh = a1h@Wh2+bh2; col = tid ----
    float accg2[MROWS] = {}, acch2[MROWS] = {};
    for (int k = 0; k < HT_; k += 4) {
      float agv[MROWS][4], ahv[MROWS][4];
      #pragma unroll
      for (int r = 0; r < MROWS; ++r) {
        float4 tg = *(const float4*)&a1g[r][k];
        agv[r][0] = tg.x; agv[r][1] = tg.y; agv[r][2] = tg.z; agv[r][3] = tg.w;
        float4 th = *(const float4*)&a1h[r][k];
        ahv[r][0] = th.x; ahv[r][1] = th.y; ahv[r][2] = th.z; ahv[r][3] = th.w;
      }
      #pragma unroll
      for (int kk = 0; kk < 4; ++kk) {
        const size_t kw = (size_t)(k + kk) * L_;
        const float wg = Wg2[kw + tid], wh = Wh2[kw + tid];
        #pragma unroll
        for (int r = 0; r < MROWS; ++r) {
          accg2[r] += agv[r][kk] * wg;
          acch2[r] += ahv[r][kk] * wh;
        }
      }
    }
    float greg[MROWS], hhreg[MROWS];
    #pragma unroll
    for (int r = 0; r < MROWS; ++r) {
      greg[r] = sigmoidf_(accg2[r] + bg2r);
      hhreg[r] = acch2[r] + bh2r;
      hhb[r][tid] = hhreg[r];
    }
    __syncthreads();

    // ---- Phase C: sigma_pre = relu(hh)@Ws+bs, mu_lin = z@Wmu+bmu ----
    float accs[MROWS] = {}, accm[MROWS] = {};
    for (int k = 0; k < L_; k += 4) {
      float hv[MROWS][4], zv2[MROWS][4];
      #pragma unroll
      for (int r = 0; r < MROWS; ++r) {
        float4 th = *(const float4*)&hhb[r][k];
        hv[r][0] = th.x; hv[r][1] = th.y; hv[r][2] = th.z; hv[r][3] = th.w;
        float4 tz = *(const float4*)&zb[r][k];
        zv2[r][0] = tz.x; zv2[r][1] = tz.y; zv2[r][2] = tz.z; zv2[r][3] = tz.w;
      }
      #pragma unroll
      for (int kk = 0; kk < 4; ++kk) {
        const size_t kw = (size_t)(k + kk) * L_;
        const float wsv = Ws[kw + tid], wmv = Wmu[kw + tid];
        #pragma unroll
        for (int r = 0; r < MROWS; ++r) {
          accs[r] += fmaxf(hv[r][kk], 0.f) * wsv;
          accm[r] += zv2[r][kk] * wmv;
        }
      }
    }

    // ---- combine, write outputs, advance carry ----
    float znew[MROWS];
    #pragma unroll
    for (int r = 0; r < MROWS; ++r) {
      const float sigma = softplusf_(accs[r] + bsr);
      const float mulin = accm[r] + bmur;
      const float mu = hhreg[r] * greg[r] + mulin * (1.f - greg[r]);
      const float eps = noise[((size_t)t * B_ + (b0 + r)) * L_ + tid];
      znew[r] = mu + sqrtf(sigma) * eps;
      const size_t o = ((size_t)(b0 + r) * T_ + t) * L_ + tid;
      mus[o] = mu;
      sigmas[o] = sigma;
    }
    __syncthreads();                 // all Phase-C reads of zb done
    #pragma unroll
    for (int r = 0; r < MROWS; ++r) zb[r][tid] = znew[r];
    __syncthreads();
  }
}

// ---------------------------------------------------------------------------
extern "C" void kernel_launch(void* const* d_in, const int* in_sizes, int n_in,
                              void* d_out, int out_size, void* d_ws, size_t ws_size,
                              hipStream_t stream)
{
  (void)in_sizes; (void)n_in; (void)d_ws; (void)ws_size; (void)out_size;
  const float* z_hat  = (const float*)d_in[0];
  const float* noise  = (const float*)d_in[1];
  const float* z_init = (const float*)d_in[2];
  const float* We1 = (const float*)d_in[3];  const float* be1 = (const float*)d_in[4];
  const float* We2 = (const float*)d_in[5];  const float* be2 = (const float*)d_in[6];
  const float* We3 = (const float*)d_in[7];  const float* be3 = (const float*)d_in[8];
  const float* Wg1 = (const float*)d_in[9];  const float* bg1 = (const float*)d_in[10];
  const float* Wg2 = (const float*)d_in[11]; const float* bg2 = (const float*)d_in[12];
  const float* Wh1 = (const float*)d_in[13]; const float* bh1 = (const float*)d_in[14];
  const float* Wh2 = (const float*)d_in[15]; const float* bh2 = (const float*)d_in[16];
  const float* Wmu = (const float*)d_in[17]; const float* bmu = (const float*)d_in[18];
  const float* Ws  = (const float*)d_in[19]; const float* bs  = (const float*)d_in[20];

  float* out    = (float*)d_out;
  float* xhat   = out;
  float* mus    = out + (size_t)B_ * T_ * OUT_;
  float* sigmas = mus + (size_t)B_ * T_ * L_;

  hipLaunchKernelGGL(transition_kernel, dim3(B_ / MROWS), dim3(256), 0, stream,
                     noise, z_init, Wg1, bg1, Wg2, bg2, Wh1, bh1, Wh2, bh2,
                     Wmu, bmu, Ws, bs, mus, sigmas);
  hipLaunchKernelGGL(emission_kernel, dim3((B_ * T_) / EROWS), dim3(256), 0, stream,
                     z_hat, We1, be1, We2, be2, We3, be3, xhat);
}

// Round 2
// 6647.666 us; speedup vs baseline: 2.5644x; 2.5644x over previous
//
#include <hip/hip_runtime.h>
#include <cstddef>

#define B_ 512
#define T_ 256
#define L_ 256
#define HE_ 256
#define HT_ 512
#define OUT_ 88

__device__ __forceinline__ float sigmoidf_(float x) { return 1.f / (1.f + expf(-x)); }
// jax.nn.softplus = max(x,0) + log1p(exp(-|x|))
__device__ __forceinline__ float softplusf_(float x) { return fmaxf(x, 0.f) + log1pf(expf(-fabsf(x))); }

// ---------------------------------------------------------------------------
// Emission: 3-layer MLP over 131072 independent rows. (unchanged from R1;
// ~387us, ~67% of fp32 vector peak)
// ---------------------------------------------------------------------------
#define EROWS 32

__device__ __forceinline__ void mlp_layer256(
    const float (*__restrict__ src)[256], float (*__restrict__ dst)[256],
    const float* __restrict__ W, const float* __restrict__ bias,
    int cx, int ry, bool do_relu)
{
  float acc[8][4] = {};
  for (int k = 0; k < 256; k += 4) {
    float sv[8][4];
    #pragma unroll
    for (int r = 0; r < 8; ++r) {
      float4 tv = *(const float4*)&src[ry * 8 + r][k];
      sv[r][0] = tv.x; sv[r][1] = tv.y; sv[r][2] = tv.z; sv[r][3] = tv.w;
    }
    #pragma unroll
    for (int kk = 0; kk < 4; ++kk) {
      float4 w = *(const float4*)&W[(size_t)(k + kk) * 256 + cx * 4];
      float wa[4] = {w.x, w.y, w.z, w.w};
      #pragma unroll
      for (int r = 0; r < 8; ++r) {
        #pragma unroll
        for (int j = 0; j < 4; ++j) acc[r][j] += sv[r][kk] * wa[j];
      }
    }
  }
  float4 bv = *(const float4*)&bias[cx * 4];
  float ba[4] = {bv.x, bv.y, bv.z, bv.w};
  #pragma unroll
  for (int r = 0; r < 8; ++r) {
    float v[4];
    #pragma unroll
    for (int j = 0; j < 4; ++j) {
      v[j] = acc[r][j] + ba[j];
      if (do_relu) v[j] = fmaxf(v[j], 0.f);
    }
    *(float4*)&dst[ry * 8 + r][cx * 4] = make_float4(v[0], v[1], v[2], v[3]);
  }
}

__global__ __launch_bounds__(256) void emission_kernel(
    const float* __restrict__ zhat,
    const float* __restrict__ We1, const float* __restrict__ be1,
    const float* __restrict__ We2, const float* __restrict__ be2,
    const float* __restrict__ We3, const float* __restrict__ be3,
    float* __restrict__ xhat)
{
  __shared__ __align__(16) float buf0[EROWS][256];
  __shared__ __align__(16) float buf1[EROWS][256];
  const int tid = threadIdx.x;
  const size_t row0 = (size_t)blockIdx.x * EROWS;

  {
    const float* src = zhat + row0 * 256;
    float* flat = &buf0[0][0];
    #pragma unroll
    for (int it = 0; it < 8; ++it) {
      int i = tid * 4 + it * 1024;
      *(float4*)&flat[i] = *(const float4*)&src[i];
    }
  }
  __syncthreads();

  const int cx = tid & 63;
  const int ry = tid >> 6;

  mlp_layer256(buf0, buf1, We1, be1, cx, ry, true);
  __syncthreads();
  mlp_layer256(buf1, buf0, We2, be2, cx, ry, true);
  __syncthreads();

  {
    const int lane = tid & 63;
    const bool has2 = (lane + 64) < OUT_;
    float acc1[8] = {}, acc2[8] = {};
    for (int k = 0; k < 256; k += 4) {
      float sv[8][4];
      #pragma unroll
      for (int r = 0; r < 8; ++r) {
        float4 tv = *(const float4*)&buf0[ry * 8 + r][k];
        sv[r][0] = tv.x; sv[r][1] = tv.y; sv[r][2] = tv.z; sv[r][3] = tv.w;
      }
      #pragma unroll
      for (int kk = 0; kk < 4; ++kk) {
        const size_t kw = (size_t)(k + kk) * OUT_;
        const float w1 = We3[kw + lane];
        const float w2 = has2 ? We3[kw + lane + 64] : 0.f;
        #pragma unroll
        for (int r = 0; r < 8; ++r) {
          acc1[r] += sv[r][kk] * w1;
          acc2[r] += sv[r][kk] * w2;
        }
      }
    }
    const float b1 = be3[lane];
    const float b2 = has2 ? be3[lane + 64] : 0.f;
    #pragma unroll
    for (int r = 0; r < 8; ++r) {
      const size_t orow = (row0 + ry * 8 + r) * OUT_;
      xhat[orow + lane] = sigmoidf_(acc1[r] + b1);
      if (has2) xhat[orow + lane + 64] = sigmoidf_(acc2[r] + b2);
    }
  }
}

// ---------------------------------------------------------------------------
// Transition scan, restructured: 128 blocks x 512 threads (8 waves/CU on 128
// CUs, 2/SIMD for latency hiding). MROWS=4 rows per block. Each float4 weight
// load feeds 16 FMAs (4 cols x 4 rows). Split-K partials reduced via a 32KB
// LDS scratch shared by all three matmul phases.
//
// Phase A: [4x256] @ Wg1/Wh1 [256x512]. Thread: cg=tid&127 (4 cols), path
//          p=(tid>>7)&1 (g|h), kq=tid>>8 (K split in 2 halves of 128).
// Phase B: [4x512] @ Wg2/Wh2 [512x256]. cg=tid&63, p=(tid>>6)&1, kq=tid>>7
//          (K split in 4 quarters of 128).
// Phase C: relu(hh)@Ws | z@Wmu [256x256]. Same decode as B, K quarters of 64.
// All LDS activation reads are wave-broadcasts (same addr across lanes).
// ---------------------------------------------------------------------------
#define MROWS 4

__global__ __launch_bounds__(512) void transition_kernel(
    const float* __restrict__ noise, const float* __restrict__ z_init,
    const float* __restrict__ Wg1, const float* __restrict__ bg1,
    const float* __restrict__ Wg2, const float* __restrict__ bg2,
    const float* __restrict__ Wh1, const float* __restrict__ bh1,
    const float* __restrict__ Wh2, const float* __restrict__ bh2,
    const float* __restrict__ Wmu, const float* __restrict__ bmu,
    const float* __restrict__ Ws, const float* __restrict__ bs,
    float* __restrict__ mus, float* __restrict__ sigmas)
{
  __shared__ __align__(16) float zb[MROWS][L_];      // 4KB carry
  __shared__ __align__(16) float a1g[MROWS][HT_];    // 8KB
  __shared__ __align__(16) float a1h[MROWS][HT_];    // 8KB
  __shared__ __align__(16) float gb[MROWS][L_];      // 4KB gate
  __shared__ __align__(16) float hb[MROWS][L_];      // 4KB hh
  __shared__ __align__(16) float scratch[8192];      // 32KB split-K partials

  const int tid = threadIdx.x;
  const int b0 = blockIdx.x * MROWS;

  // Phase A decode
  const int cgA = tid & 127;
  const int pA_ = (tid >> 7) & 1;
  const int kqA = tid >> 8;
  const float* __restrict__ W1 = pA_ ? Wh1 : Wg1;

  // Phase B/C decode
  const int cgB = tid & 63;
  const int pB_ = (tid >> 6) & 1;
  const int kqB = tid >> 7;
  const float* __restrict__ W2 = pB_ ? Wh2 : Wg2;
  const float* __restrict__ W3 = pB_ ? Wmu : Ws;   // p=0: sigma path, p=1: mu-lin path

  // load z_init
  for (int i = tid; i < MROWS * L_; i += 512)
    zb[i >> 8][i & 255] = z_init[(size_t)(b0 + (i >> 8)) * L_ + (i & 255)];
  __syncthreads();

  for (int t = 0; t < T_; ++t) {
    // ================= Phase A partials =================
    {
      float acc[MROWS][4] = {};
      const int k0 = kqA * 128;
      #pragma unroll 2
      for (int k = k0; k < k0 + 128; k += 4) {
        float zv[MROWS][4];
        #pragma unroll
        for (int r = 0; r < MROWS; ++r) {
          float4 tv = *(const float4*)&zb[r][k];
          zv[r][0] = tv.x; zv[r][1] = tv.y; zv[r][2] = tv.z; zv[r][3] = tv.w;
        }
        #pragma unroll
        for (int kk = 0; kk < 4; ++kk) {
          float4 w = *(const float4*)&W1[(size_t)(k + kk) * HT_ + cgA * 4];
          float wa[4] = {w.x, w.y, w.z, w.w};
          #pragma unroll
          for (int r = 0; r < MROWS; ++r)
            #pragma unroll
            for (int j = 0; j < 4; ++j) acc[r][j] += zv[r][kk] * wa[j];
        }
      }
      #pragma unroll
      for (int r = 0; r < MROWS; ++r)
        *(float4*)&scratch[(size_t)(((kqA * 2 + pA_) * 4 + r) * 512) + cgA * 4] =
            make_float4(acc[r][0], acc[r][1], acc[r][2], acc[r][3]);
    }
    __syncthreads();

    // ---- finalize A: a1g/a1h = relu(sum partials + bias) ----
    #pragma unroll
    for (int i = 0; i < 8; ++i) {
      int idx = tid + i * 512;
      int c = idx & 511; int rp = idx >> 9; int r = rp & 3; int p = rp >> 2;
      float v = scratch[((0 * 2 + p) * 4 + r) * 512 + c]
              + scratch[((1 * 2 + p) * 4 + r) * 512 + c]
              + (p ? bh1[c] : bg1[c]);
      v = fmaxf(v, 0.f);
      if (p) a1h[r][c] = v; else a1g[r][c] = v;
    }
    __syncthreads();

    // ================= Phase B partials =================
    {
      const float (*__restrict__ srcB)[HT_] = pB_ ? a1h : a1g;
      float acc[MROWS][4] = {};
      const int k0 = kqB * 128;
      #pragma unroll 2
      for (int k = k0; k < k0 + 128; k += 4) {
        float av[MROWS][4];
        #pragma unroll
        for (int r = 0; r < MROWS; ++r) {
          float4 tv = *(const float4*)&srcB[r][k];
          av[r][0] = tv.x; av[r][1] = tv.y; av[r][2] = tv.z; av[r][3] = tv.w;
        }
        #pragma unroll
        for (int kk = 0; kk < 4; ++kk) {
          float4 w = *(const float4*)&W2[(size_t)(k + kk) * L_ + cgB * 4];
          float wa[4] = {w.x, w.y, w.z, w.w};
          #pragma unroll
          for (int r = 0; r < MROWS; ++r)
            #pragma unroll
            for (int j = 0; j < 4; ++j) acc[r][j] += av[r][kk] * wa[j];
        }
      }
      #pragma unroll
      for (int r = 0; r < MROWS; ++r)
        *(float4*)&scratch[(size_t)(((kqB * 2 + pB_) * 4 + r) * 256) + cgB * 4] =
            make_float4(acc[r][0], acc[r][1], acc[r][2], acc[r][3]);
    }
    __syncthreads();

    // ---- finalize B: gb = sigmoid(.), hb = raw ----
    #pragma unroll
    for (int i = 0; i < 4; ++i) {
      int idx = tid + i * 512;
      int c = idx & 255; int rp = idx >> 8; int r = rp & 3; int p = rp >> 2;
      float s = scratch[((0 * 2 + p) * 4 + r) * 256 + c]
              + scratch[((1 * 2 + p) * 4 + r) * 256 + c]
              + scratch[((2 * 2 + p) * 4 + r) * 256 + c]
              + scratch[((3 * 2 + p) * 4 + r) * 256 + c];
      if (p) hb[r][c] = s + bh2[c];
      else   gb[r][c] = sigmoidf_(s + bg2[c]);
    }
    __syncthreads();

    // ================= Phase C partials =================
    {
      float acc[MROWS][4] = {};
      const int k0 = kqB * 64;
      #pragma unroll 2
      for (int k = k0; k < k0 + 64; k += 4) {
        float sv[MROWS][4];
        #pragma unroll
        for (int r = 0; r < MROWS; ++r) {
          if (pB_) {                       // mu-lin path reads z
            float4 tv = *(const float4*)&zb[r][k];
            sv[r][0] = tv.x; sv[r][1] = tv.y; sv[r][2] = tv.z; sv[r][3] = tv.w;
          } else {                         // sigma path reads relu(hh)
            float4 tv = *(const float4*)&hb[r][k];
            sv[r][0] = fmaxf(tv.x, 0.f); sv[r][1] = fmaxf(tv.y, 0.f);
            sv[r][2] = fmaxf(tv.z, 0.f); sv[r][3] = fmaxf(tv.w, 0.f);
          }
        }
        #pragma unroll
        for (int kk = 0; kk < 4; ++kk) {
          float4 w = *(const float4*)&W3[(size_t)(k + kk) * L_ + cgB * 4];
          float wa[4] = {w.x, w.y, w.z, w.w};
          #pragma unroll
          for (int r = 0; r < MROWS; ++r)
            #pragma unroll
            for (int j = 0; j < 4; ++j) acc[r][j] += sv[r][kk] * wa[j];
        }
      }
      #pragma unroll
      for (int r = 0; r < MROWS; ++r)
        *(float4*)&scratch[(size_t)(((kqB * 2 + pB_) * 4 + r) * 256) + cgB * 4] =
            make_float4(acc[r][0], acc[r][1], acc[r][2], acc[r][3]);
    }
    __syncthreads();

    // ---- finalize C: combine, write outputs, advance carry ----
    #pragma unroll
    for (int i = 0; i < 2; ++i) {
      int idx = tid + i * 512;
      int c = idx & 255; int r = idx >> 8;
      float sp = scratch[((0 * 2 + 0) * 4 + r) * 256 + c]
               + scratch[((1 * 2 + 0) * 4 + r) * 256 + c]
               + scratch[((2 * 2 + 0) * 4 + r) * 256 + c]
               + scratch[((3 * 2 + 0) * 4 + r) * 256 + c] + bs[c];
      float ml = scratch[((0 * 2 + 1) * 4 + r) * 256 + c]
               + scratch[((1 * 2 + 1) * 4 + r) * 256 + c]
               + scratch[((2 * 2 + 1) * 4 + r) * 256 + c]
               + scratch[((3 * 2 + 1) * 4 + r) * 256 + c] + bmu[c];
      float g = gb[r][c], h = hb[r][c];
      float sigma = softplusf_(sp);
      float mu = h * g + ml * (1.f - g);
      float eps = noise[((size_t)t * B_ + (b0 + r)) * L_ + c];
      float zn = mu + sqrtf(sigma) * eps;
      size_t o = ((size_t)(b0 + r) * T_ + t) * L_ + c;
      mus[o] = mu;
      sigmas[o] = sigma;
      zb[r][c] = zn;   // zb reads all completed before previous barrier
    }
    __syncthreads();
  }
}

// ---------------------------------------------------------------------------
extern "C" void kernel_launch(void* const* d_in, const int* in_sizes, int n_in,
                              void* d_out, int out_size, void* d_ws, size_t ws_size,
                              hipStream_t stream)
{
  (void)in_sizes; (void)n_in; (void)d_ws; (void)ws_size; (void)out_size;
  const float* z_hat  = (const float*)d_in[0];
  const float* noise  = (const float*)d_in[1];
  const float* z_init = (const float*)d_in[2];
  const float* We1 = (const float*)d_in[3];  const float* be1 = (const float*)d_in[4];
  const float* We2 = (const float*)d_in[5];  const float* be2 = (const float*)d_in[6];
  const float* We3 = (const float*)d_in[7];  const float* be3 = (const float*)d_in[8];
  const float* Wg1 = (const float*)d_in[9];  const float* bg1 = (const float*)d_in[10];
  const float* Wg2 = (const float*)d_in[11]; const float* bg2 = (const float*)d_in[12];
  const float* Wh1 = (const float*)d_in[13]; const float* bh1 = (const float*)d_in[14];
  const float* Wh2 = (const float*)d_in[15]; const float* bh2 = (const float*)d_in[16];
  const float* Wmu = (const float*)d_in[17]; const float* bmu = (const float*)d_in[18];
  const float* Ws  = (const float*)d_in[19]; const float* bs  = (const float*)d_in[20];

  float* out    = (float*)d_out;
  float* xhat   = out;
  float* mus    = out + (size_t)B_ * T_ * OUT_;
  float* sigmas = mus + (size_t)B_ * T_ * L_;

  hipLaunchKernelGGL(transition_kernel, dim3(B_ / MROWS), dim3(512), 0, stream,
                     noise, z_init, Wg1, bg1, Wg2, bg2, Wh1, bh1, Wh2, bh2,
                     Wmu, bmu, Ws, bs, mus, sigmas);
  hipLaunchKernelGGL(emission_kernel, dim3((B_ * T_) / EROWS), dim3(256), 0, stream,
                     z_hat, We1, be1, We2, be2, We3, be3, xhat);
}

// Round 3
// 6346.743 us; speedup vs baseline: 2.6860x; 1.0474x over previous
//
#include <hip/hip_runtime.h>
#include <cstddef>

#define B_ 512
#define T_ 256
#define L_ 256
#define HT_ 512
#define OUT_ 88

#define MROWS 4
#define NTB (B_ / MROWS)          // 128 transition blocks
#define EROWS 32
#define NEB ((B_ * T_) / EROWS)   // 4096 emission blocks

__device__ __forceinline__ float sigmoidf_(float x) { return 1.f / (1.f + expf(-x)); }
// jax.nn.softplus = max(x,0) + log1p(exp(-|x|))
__device__ __forceinline__ float softplusf_(float x) { return fmaxf(x, 0.f) + log1pf(expf(-fabsf(x))); }

// ---------------------------------------------------------------------------
// Emission layer helper: 256->256, relu. 1024 threads: cx=tid&63 owns 4 cols,
// ry=tid>>6 (0..15) owns rows {ry*2, ry*2+1}. LDS activation reads are
// wave-broadcasts; weight float4 reads coalesced (lane = cx).
// ---------------------------------------------------------------------------
__device__ __forceinline__ void em_layer256(
    const float (*__restrict__ src)[256], float (*__restrict__ dst)[256],
    const float* __restrict__ W, const float* __restrict__ bias,
    int cx, int ry)
{
  float acc[2][4] = {};
  for (int k = 0; k < 256; k += 4) {
    float sv[2][4];
    #pragma unroll
    for (int r = 0; r < 2; ++r) {
      float4 tv = *(const float4*)&src[ry * 2 + r][k];
      sv[r][0] = tv.x; sv[r][1] = tv.y; sv[r][2] = tv.z; sv[r][3] = tv.w;
    }
    #pragma unroll
    for (int kk = 0; kk < 4; ++kk) {
      float4 w = *(const float4*)&W[(size_t)(k + kk) * 256 + cx * 4];
      float wa[4] = {w.x, w.y, w.z, w.w};
      #pragma unroll
      for (int r = 0; r < 2; ++r)
        #pragma unroll
        for (int j = 0; j < 4; ++j) acc[r][j] += sv[r][kk] * wa[j];
    }
  }
  float4 bv = *(const float4*)&bias[cx * 4];
  float ba[4] = {bv.x, bv.y, bv.z, bv.w};
  #pragma unroll
  for (int r = 0; r < 2; ++r) {
    float v[4];
    #pragma unroll
    for (int j = 0; j < 4; ++j) v[j] = fmaxf(acc[r][j] + ba[j], 0.f);
    *(float4*)&dst[ry * 2 + r][cx * 4] = make_float4(v[0], v[1], v[2], v[3]);
  }
}

// ---------------------------------------------------------------------------
// Fused kernel. Blocks [0,128): transition scan (1024 thr, 16 waves = 4/SIMD,
// 94KB LDS -> exactly 1 block/CU, so the 128 scan blocks own 128 CUs and
// emission blocks can never co-reside there). Blocks [128, 4224): emission
// MLP on the other 128 CUs, fully hidden under the ~3ms scan.
// ---------------------------------------------------------------------------
__global__ __launch_bounds__(1024, 4) void fused_kernel(
    const float* __restrict__ zhat,
    const float* __restrict__ noise, const float* __restrict__ z_init,
    const float* __restrict__ We1, const float* __restrict__ be1,
    const float* __restrict__ We2, const float* __restrict__ be2,
    const float* __restrict__ We3, const float* __restrict__ be3,
    const float* __restrict__ Wg1, const float* __restrict__ bg1,
    const float* __restrict__ Wg2, const float* __restrict__ bg2,
    const float* __restrict__ Wh1, const float* __restrict__ bh1,
    const float* __restrict__ Wh2, const float* __restrict__ bh2,
    const float* __restrict__ Wmu, const float* __restrict__ bmu,
    const float* __restrict__ Ws, const float* __restrict__ bs,
    float* __restrict__ xhat, float* __restrict__ mus, float* __restrict__ sigmas)
{
  // union pool: transition needs 94208B; emission needs 65536B
  __shared__ __align__(16) char pool[94208];
  const int tid = threadIdx.x;

  if (blockIdx.x < NTB) {
    // ================= TRANSITION SCAN =================
    float (*zb)[L_]   = (float(*)[L_])(pool);                  // 4KB carry
    float (*a1g)[HT_] = (float(*)[HT_])(pool + 4096);          // 8KB
    float (*a1h)[HT_] = (float(*)[HT_])(pool + 12288);         // 8KB
    float (*gb)[L_]   = (float(*)[L_])(pool + 20480);          // 4KB
    float (*hb)[L_]   = (float(*)[L_])(pool + 24576);          // 4KB
    float* scratch    = (float*)(pool + 28672);                // 64KB split-K

    const int b0 = blockIdx.x * MROWS;

    // Phase A decode: cg (4 cols of 512), path g|h, K split 4x64
    const int cgA = tid & 127;
    const int pA_ = (tid >> 7) & 1;
    const int kqA = tid >> 8;
    const float* __restrict__ W1 = pA_ ? Wh1 : Wg1;
    // Phase B/C decode: cg (4 cols of 256), path, K split 8-way
    const int cgB = tid & 63;
    const int pB_ = (tid >> 6) & 1;
    const int kqB = tid >> 7;
    const float* __restrict__ W2 = pB_ ? Wh2 : Wg2;
    const float* __restrict__ W3 = pB_ ? Wmu : Ws;   // p=0 sigma, p=1 mu-lin

    zb[tid >> 8][tid & 255] = z_init[(size_t)(b0 + (tid >> 8)) * L_ + (tid & 255)];
    __syncthreads();

    for (int t = 0; t < T_; ++t) {
      // ---- Phase A partials: [4x256] @ {Wg1,Wh1} [256x512] ----
      {
        float acc[MROWS][4] = {};
        const int k0 = kqA * 64;
        #pragma unroll 2
        for (int k = k0; k < k0 + 64; k += 4) {
          float zv[MROWS][4];
          #pragma unroll
          for (int r = 0; r < MROWS; ++r) {
            float4 tv = *(const float4*)&zb[r][k];
            zv[r][0] = tv.x; zv[r][1] = tv.y; zv[r][2] = tv.z; zv[r][3] = tv.w;
          }
          #pragma unroll
          for (int kk = 0; kk < 4; ++kk) {
            float4 w = *(const float4*)&W1[(size_t)(k + kk) * HT_ + cgA * 4];
            float wa[4] = {w.x, w.y, w.z, w.w};
            #pragma unroll
            for (int r = 0; r < MROWS; ++r)
              #pragma unroll
              for (int j = 0; j < 4; ++j) acc[r][j] += zv[r][kk] * wa[j];
          }
        }
        #pragma unroll
        for (int r = 0; r < MROWS; ++r)
          *(float4*)&scratch[(((kqA * 2 + pA_) * 4 + r) * 512) + cgA * 4] =
              make_float4(acc[r][0], acc[r][1], acc[r][2], acc[r][3]);
      }
      __syncthreads();

      // ---- finalize A: a1g/a1h = relu(sum 4 partials + bias) ----
      #pragma unroll
      for (int i = 0; i < 4; ++i) {
        int idx = tid + i * 1024;
        int c = idx & 511; int rp = idx >> 9; int r = rp & 3; int p = rp >> 2;
        float v = scratch[((0 * 2 + p) * 4 + r) * 512 + c]
                + scratch[((1 * 2 + p) * 4 + r) * 512 + c]
                + scratch[((2 * 2 + p) * 4 + r) * 512 + c]
                + scratch[((3 * 2 + p) * 4 + r) * 512 + c]
                + (p ? bh1[c] : bg1[c]);
        v = fmaxf(v, 0.f);
        if (p) a1h[r][c] = v; else a1g[r][c] = v;
      }
      __syncthreads();

      // ---- Phase B partials: [4x512] @ {Wg2,Wh2} [512x256] ----
      {
        const float (*__restrict__ srcB)[HT_] = pB_ ? a1h : a1g;
        float acc[MROWS][4] = {};
        const int k0 = kqB * 64;
        #pragma unroll 2
        for (int k = k0; k < k0 + 64; k += 4) {
          float av[MROWS][4];
          #pragma unroll
          for (int r = 0; r < MROWS; ++r) {
            float4 tv = *(const float4*)&srcB[r][k];
            av[r][0] = tv.x; av[r][1] = tv.y; av[r][2] = tv.z; av[r][3] = tv.w;
          }
          #pragma unroll
          for (int kk = 0; kk < 4; ++kk) {
            float4 w = *(const float4*)&W2[(size_t)(k + kk) * L_ + cgB * 4];
            float wa[4] = {w.x, w.y, w.z, w.w};
            #pragma unroll
            for (int r = 0; r < MROWS; ++r)
              #pragma unroll
              for (int j = 0; j < 4; ++j) acc[r][j] += av[r][kk] * wa[j];
          }
        }
        #pragma unroll
        for (int r = 0; r < MROWS; ++r)
          *(float4*)&scratch[(((kqB * 2 + pB_) * 4 + r) * 256) + cgB * 4] =
              make_float4(acc[r][0], acc[r][1], acc[r][2], acc[r][3]);
      }
      __syncthreads();

      // ---- finalize B: gb = sigmoid(sum8+bias), hb = sum8+bias ----
      #pragma unroll
      for (int i = 0; i < 2; ++i) {
        int idx = tid + i * 1024;
        int c = idx & 255; int rp = idx >> 8; int r = rp & 3; int p = rp >> 2;
        float s = 0.f;
        #pragma unroll
        for (int kq = 0; kq < 8; ++kq)
          s += scratch[((kq * 2 + p) * 4 + r) * 256 + c];
        if (p) hb[r][c] = s + bh2[c];
        else   gb[r][c] = sigmoidf_(s + bg2[c]);
      }
      __syncthreads();

      // ---- Phase C partials: relu(hh)@Ws | z@Wmu, [256x256] ----
      {
        float acc[MROWS][4] = {};
        const int k0 = kqB * 32;
        #pragma unroll 2
        for (int k = k0; k < k0 + 32; k += 4) {
          float sv[MROWS][4];
          #pragma unroll
          for (int r = 0; r < MROWS; ++r) {
            if (pB_) {
              float4 tv = *(const float4*)&zb[r][k];
              sv[r][0] = tv.x; sv[r][1] = tv.y; sv[r][2] = tv.z; sv[r][3] = tv.w;
            } else {
              float4 tv = *(const float4*)&hb[r][k];
              sv[r][0] = fmaxf(tv.x, 0.f); sv[r][1] = fmaxf(tv.y, 0.f);
              sv[r][2] = fmaxf(tv.z, 0.f); sv[r][3] = fmaxf(tv.w, 0.f);
            }
          }
          #pragma unroll
          for (int kk = 0; kk < 4; ++kk) {
            float4 w = *(const float4*)&W3[(size_t)(k + kk) * L_ + cgB * 4];
            float wa[4] = {w.x, w.y, w.z, w.w};
            #pragma unroll
            for (int r = 0; r < MROWS; ++r)
              #pragma unroll
              for (int j = 0; j < 4; ++j) acc[r][j] += sv[r][kk] * wa[j];
          }
        }
        #pragma unroll
        for (int r = 0; r < MROWS; ++r)
          *(float4*)&scratch[(((kqB * 2 + pB_) * 4 + r) * 256) + cgB * 4] =
              make_float4(acc[r][0], acc[r][1], acc[r][2], acc[r][3]);
      }
      __syncthreads();

      // ---- finalize C: combine, write outputs, advance carry ----
      {
        int c = tid & 255; int r = tid >> 8;
        float sp = bs[c], ml = bmu[c];
        #pragma unroll
        for (int kq = 0; kq < 8; ++kq) {
          sp += scratch[((kq * 2 + 0) * 4 + r) * 256 + c];
          ml += scratch[((kq * 2 + 1) * 4 + r) * 256 + c];
        }
        float g = gb[r][c], h = hb[r][c];
        float sigma = softplusf_(sp);
        float mu = h * g + ml * (1.f - g);
        float eps = noise[((size_t)t * B_ + (b0 + r)) * L_ + c];
        size_t o = ((size_t)(b0 + r) * T_ + t) * L_ + c;
        mus[o] = mu;
        sigmas[o] = sigma;
        zb[r][c] = mu + sqrtf(sigma) * eps;  // zb reads all done pre-barrier
      }
      __syncthreads();
    }
  } else {
    // ================= EMISSION MLP =================
    float (*buf0)[256] = (float(*)[256])(pool);
    float (*buf1)[256] = (float(*)[256])(pool + 32768);
    const size_t row0 = (size_t)(blockIdx.x - NTB) * EROWS;

    { // load 32x256 tile, coalesced float4
      const float* src = zhat + row0 * 256;
      float* flat = &buf0[0][0];
      #pragma unroll
      for (int it = 0; it < 2; ++it) {
        int i = (tid + it * 1024) * 4;
        *(float4*)&flat[i] = *(const float4*)&src[i];
      }
    }
    __syncthreads();

    const int cx = tid & 63;
    const int ry = tid >> 6;   // 0..15, rows {ry*2, ry*2+1}

    em_layer256(buf0, buf1, We1, be1, cx, ry);
    __syncthreads();
    em_layer256(buf1, buf0, We2, be2, cx, ry);
    __syncthreads();

    { // layer 3: 256 -> 88, sigmoid
      const int lane = tid & 63;
      const bool has2 = (lane + 64) < OUT_;
      float acc1[2] = {}, acc2[2] = {};
      for (int k = 0; k < 256; k += 4) {
        float sv[2][4];
        #pragma unroll
        for (int r = 0; r < 2; ++r) {
          float4 tv = *(const float4*)&buf0[ry * 2 + r][k];
          sv[r][0] = tv.x; sv[r][1] = tv.y; sv[r][2] = tv.z; sv[r][3] = tv.w;
        }
        #pragma unroll
        for (int kk = 0; kk < 4; ++kk) {
          const size_t kw = (size_t)(k + kk) * OUT_;
          const float w1 = We3[kw + lane];
          const float w2 = has2 ? We3[kw + lane + 64] : 0.f;
          #pragma unroll
          for (int r = 0; r < 2; ++r) {
            acc1[r] += sv[r][kk] * w1;
            acc2[r] += sv[r][kk] * w2;
          }
        }
      }
      const float b1 = be3[lane];
      const float b2 = has2 ? be3[lane + 64] : 0.f;
      #pragma unroll
      for (int r = 0; r < 2; ++r) {
        const size_t orow = (row0 + ry * 2 + r) * OUT_;
        xhat[orow + lane] = sigmoidf_(acc1[r] + b1);
        if (has2) xhat[orow + lane + 64] = sigmoidf_(acc2[r] + b2);
      }
    }
  }
}

// ---------------------------------------------------------------------------
extern "C" void kernel_launch(void* const* d_in, const int* in_sizes, int n_in,
                              void* d_out, int out_size, void* d_ws, size_t ws_size,
                              hipStream_t stream)
{
  (void)in_sizes; (void)n_in; (void)d_ws; (void)ws_size; (void)out_size;
  const float* z_hat  = (const float*)d_in[0];
  const float* noise  = (const float*)d_in[1];
  const float* z_init = (const float*)d_in[2];
  const float* We1 = (const float*)d_in[3];  const float* be1 = (const float*)d_in[4];
  const float* We2 = (const float*)d_in[5];  const float* be2 = (const float*)d_in[6];
  const float* We3 = (const float*)d_in[7];  const float* be3 = (const float*)d_in[8];
  const float* Wg1 = (const float*)d_in[9];  const float* bg1 = (const float*)d_in[10];
  const float* Wg2 = (const float*)d_in[11]; const float* bg2 = (const float*)d_in[12];
  const float* Wh1 = (const float*)d_in[13]; const float* bh1 = (const float*)d_in[14];
  const float* Wh2 = (const float*)d_in[15]; const float* bh2 = (const float*)d_in[16];
  const float* Wmu = (const float*)d_in[17]; const float* bmu = (const float*)d_in[18];
  const float* Ws  = (const float*)d_in[19]; const float* bs  = (const float*)d_in[20];

  float* out    = (float*)d_out;
  float* xhat   = out;
  float* mus    = out + (size_t)B_ * T_ * OUT_;
  float* sigmas = mus + (size_t)B_ * T_ * L_;

  hipLaunchKernelGGL(fused_kernel, dim3(NTB + NEB), dim3(1024), 0, stream,
                     z_hat, noise, z_init, We1, be1, We2, be2, We3, be3,
                     Wg1, bg1, Wg2, bg2, Wh1, bh1, Wh2, bh2,
                     Wmu, bmu, Ws, bs, xhat, mus, sigmas);
}